// Round 4
// baseline (1816.466 us; speedup 1.0000x reference)
//
#include <hip/hip_runtime.h>
#include <math.h>

// Problem constants
#define BB 128
#define SS 64
#define EE 300
#define HH 512
#define LL 5
#define BSH (BB*SS*HH)   // 4,194,304
#define KP  320          // E padded to multiple of 32 for bf16 MFMA
#define NGRP 8           // independent chain-groups (16 chains each)
#define BPG  24          // blocks per group (8 N-tiles x 3 gates)
#define GRID_FUSED (NGRP*BPG)   // 192

typedef __attribute__((ext_vector_type(8))) short bf16x8;        // 8 bf16 = 4 VGPRs
typedef __attribute__((ext_vector_type(4))) float f32x4;
typedef __attribute__((ext_vector_type(4))) unsigned int u32x4;  // 16B staging

__device__ __forceinline__ float fast_sigmoid(float x) {
    return 1.0f / (1.0f + __expf(-x));
}
__device__ __forceinline__ float fast_tanh(float x) {
    x = fminf(fmaxf(x, -20.0f), 20.0f);
    float e = __expf(2.0f * x);
    return (e - 1.0f) / (e + 1.0f);
}
// fp32 -> bf16 round-to-nearest-even (bit trick; inputs finite here)
__device__ __forceinline__ unsigned short f2bf(float f) {
    unsigned int u = __float_as_uint(f);
    u += 0x7fffu + ((u >> 16) & 1u);
    return (unsigned short)(u >> 16);
}
__device__ __forceinline__ float bf2f(unsigned short h) {
    return __uint_as_float((unsigned int)h << 16);
}
// Split fp32 into hi/lo bf16 pair: v ~= hi + lo, residual ~2^-18 * |v|
__device__ __forceinline__ void split2(float v, unsigned short& hi, unsigned short& lo) {
    hi = f2bf(v);
    lo = f2bf(v - bf2f(hi));
}

// ---------------------------------------------------------------------------
// Prep: (a) split 6 weight matrices into bf16 hi/lo planes (Wx padded K->320),
// (b) per-(b,t) compact active-children lists, (c) zero the barrier counters.
// ---------------------------------------------------------------------------
__global__ __launch_bounds__(256) void prep_kernel(
    const int* __restrict__ bfs, const int* __restrict__ children,
    const float* __restrict__ Wix, const float* __restrict__ Wfx, const float* __restrict__ Wux,
    const float* __restrict__ Wih, const float* __restrict__ Wfh, const float* __restrict__ Wuh,
    unsigned short* __restrict__ Wixh, unsigned short* __restrict__ Wixl,
    unsigned short* __restrict__ Wfxh, unsigned short* __restrict__ Wfxl,
    unsigned short* __restrict__ Wuxh, unsigned short* __restrict__ Wuxl,
    unsigned short* __restrict__ Wihh, unsigned short* __restrict__ Wihl,
    unsigned short* __restrict__ Wfhh, unsigned short* __restrict__ Wfhl,
    unsigned short* __restrict__ Wuhh, unsigned short* __restrict__ Wuhl,
    unsigned char* __restrict__ clist, int* __restrict__ ccnt, int* __restrict__ bars)
{
    const int gid = blockIdx.x * 256 + threadIdx.x;
    const int G = gridDim.x * 256;
    for (int i = gid; i < NGRP * 256; i += G) bars[i] = 0;
    for (int i = gid; i < 3 * HH * KP; i += G) {
        int g = i / (HH * KP), rem = i % (HH * KP), r = rem / KP, k = rem % KP;
        const float* src = (g == 0) ? Wix : (g == 1) ? Wfx : Wux;
        unsigned short* dh = (g == 0) ? Wixh : (g == 1) ? Wfxh : Wuxh;
        unsigned short* dl = (g == 0) ? Wixl : (g == 1) ? Wfxl : Wuxl;
        float v = (k < EE) ? src[(size_t)r * EE + k] : 0.0f;
        unsigned short hi, lo; split2(v, hi, lo);
        dh[r * KP + k] = hi; dl[r * KP + k] = lo;
    }
    for (int i = gid; i < 3 * HH * HH; i += G) {
        int g = i / (HH * HH), idx = i % (HH * HH);
        const float* src = (g == 0) ? Wih : (g == 1) ? Wfh : Wuh;
        unsigned short* dh = (g == 0) ? Wihh : (g == 1) ? Wfhh : Wuhh;
        unsigned short* dl = (g == 0) ? Wihl : (g == 1) ? Wfhl : Wuhl;
        unsigned short hi, lo; split2(src[idx], hi, lo);
        dh[idx] = hi; dl[idx] = lo;
    }
    if (gid < BB * SS) {
        const int b = gid >> 6, t = gid & 63;
        unsigned long long w = 0;
        for (int tp = 0; tp < t; ++tp) w |= 1ull << (bfs[b * SS + tp] & 63);
        const int cur = bfs[b * SS + t];
        const int* crow = children + (size_t)(b * SS + cur) * SS;
        unsigned char* lst = clist + (size_t)gid * SS;
        int cnt = 0;
        for (int s = 0; s < SS; ++s)
            if (crow[s] != 0 && ((w >> s) & 1ull)) lst[cnt++] = (unsigned char)s;
        ccnt[gid] = cnt;
    }
}

// ---------------------------------------------------------------------------
// XP precompute, split-bf16 MFMA. [8192 x 320pad] @ [320 x 512] per gate.
// Tile 32M x 64N, grid (256, 3). A staged once in LDS (hi/lo, full K);
// B fragments loaded DIRECTLY from global (W is 2 MB total -> L2-resident),
// so there are no per-tile staging barriers at all (2 barriers per block).
// D = Ah*Bh + Ah*Bl + Al*Bh  (lo*lo dropped, rel ~2^-18).
// ---------------------------------------------------------------------------
__global__ __launch_bounds__(256) void xp_mfma(
    const int* __restrict__ x, const float* __restrict__ embed,
    const unsigned short* __restrict__ Wixh, const unsigned short* __restrict__ Wixl,
    const unsigned short* __restrict__ Wfxh, const unsigned short* __restrict__ Wfxl,
    const unsigned short* __restrict__ Wuxh, const unsigned short* __restrict__ Wuxl,
    const float* __restrict__ bix, const float* __restrict__ bih,
    const float* __restrict__ bfx, const float* __restrict__ bfh,
    const float* __restrict__ bux, const float* __restrict__ buh,
    float* __restrict__ XPi, float* __restrict__ XPf, float* __restrict__ XPu)
{
    const int mb = blockIdx.x;            // 256 tiles of 32 rows of B*S
    const int g  = blockIdx.y;            // gate
    const unsigned short* __restrict__ Wbh = (g == 0) ? Wixh : (g == 1) ? Wfxh : Wuxh;
    const unsigned short* __restrict__ Wbl = (g == 0) ? Wixl : (g == 1) ? Wfxl : Wuxl;
    const float* __restrict__ b1 = (g == 0) ? bix : (g == 1) ? bfx : bux;
    const float* __restrict__ b2 = (g == 0) ? bih : (g == 1) ? bfh : buh;
    float* __restrict__ OUT = (g == 0) ? XPi : (g == 1) ? XPf : XPu;

    const int row0 = mb * 32;
    __shared__ unsigned short As[2][32 * 328];   // hi/lo planes, full K, pad 328
    __shared__ int toks[32];

    const int tid = threadIdx.x;
    if (tid < 32) toks[tid] = x[row0 + tid];
    __syncthreads();

    // Stage A full K: 32 rows x 300 fp32 -> split into hi/lo planes; pad to 320
    for (int i = tid; i < 32 * 75; i += 256) {
        int r = i / 75, c = i - r * 75;
        const float4 v = *(const float4*)(embed + (size_t)toks[r] * EE + c * 4);
        ushort4 hv, lv;
        split2(v.x, hv.x, lv.x); split2(v.y, hv.y, lv.y);
        split2(v.z, hv.z, lv.z); split2(v.w, hv.w, lv.w);
        *(ushort4*)&As[0][r * 328 + c * 4] = hv;
        *(ushort4*)&As[1][r * 328 + c * 4] = lv;
    }
    for (int i = tid; i < 32 * 20; i += 256) {
        int r = i / 20, k = EE + (i - r * 20);
        As[0][r * 328 + k] = 0; As[1][r * 328 + k] = 0;
    }
    __syncthreads();

    const int lane = tid & 63, wave = tid >> 6;
    const int quad = lane >> 4, col = lane & 15;
    const int wn = wave * 16;             // each wave: 16-wide N-slice, full 32 M

    for (int nt = 0; nt < 8; ++nt) {
        const int gn = nt * 64 + wn + col;        // global output column (B row)
        const size_t wrow = (size_t)gn * KP;
        f32x4 acc0 = {0.f, 0.f, 0.f, 0.f}, acc1 = {0.f, 0.f, 0.f, 0.f};
        #pragma unroll
        for (int kq = 0; kq < 10; ++kq) {         // K = 320 = 10 * 32
            const int ka = kq * 32 + quad * 8;
            bf16x8 bh  = *(const bf16x8*)(Wbh + wrow + ka);   // direct L2 load
            bf16x8 bl  = *(const bf16x8*)(Wbl + wrow + ka);
            bf16x8 a0h = *(const bf16x8*)&As[0][col * 328 + ka];
            bf16x8 a0l = *(const bf16x8*)&As[1][col * 328 + ka];
            bf16x8 a1h = *(const bf16x8*)&As[0][(16 + col) * 328 + ka];
            bf16x8 a1l = *(const bf16x8*)&As[1][(16 + col) * 328 + ka];
            acc0 = __builtin_amdgcn_mfma_f32_16x16x32_bf16(a0h, bh, acc0, 0, 0, 0);
            acc1 = __builtin_amdgcn_mfma_f32_16x16x32_bf16(a1h, bh, acc1, 0, 0, 0);
            acc0 = __builtin_amdgcn_mfma_f32_16x16x32_bf16(a0h, bl, acc0, 0, 0, 0);
            acc1 = __builtin_amdgcn_mfma_f32_16x16x32_bf16(a1h, bl, acc1, 0, 0, 0);
            acc0 = __builtin_amdgcn_mfma_f32_16x16x32_bf16(a0l, bh, acc0, 0, 0, 0);
            acc1 = __builtin_amdgcn_mfma_f32_16x16x32_bf16(a1l, bh, acc1, 0, 0, 0);
        }
        // C/D layout: col = lane&15 (N), row = quad*4 + reg (M)
        const float bb = b1[gn] + b2[gn];
        #pragma unroll
        for (int reg = 0; reg < 4; ++reg) {
            const int ml = quad * 4 + reg;
            OUT[(size_t)(row0 + ml) * HH + gn]      = acc0[reg] + bb;
            OUT[(size_t)(row0 + 16 + ml) * HH + gn] = acc1[reg] + bb;
        }
    }
}

// ---------------------------------------------------------------------------
// Group barrier: one single-use counter per (group, step, phase), zeroed by
// prep. Agent-scope fences handle cross-XCD visibility (per-XCD L2s are not
// coherent). Co-residency of all 192 blocks guaranteed by cooperative launch.
// ---------------------------------------------------------------------------
__device__ __forceinline__ void group_barrier(int* cnt) {
    __syncthreads();
    if (threadIdx.x == 0) {
        __threadfence();   // release this block's writes (L2 wb across XCDs)
        __hip_atomic_fetch_add(cnt, 1, __ATOMIC_RELAXED, __HIP_MEMORY_SCOPE_AGENT);
        while (__hip_atomic_load(cnt, __ATOMIC_RELAXED, __HIP_MEMORY_SCOPE_AGENT) < BPG)
            __builtin_amdgcn_s_sleep(2);
        __threadfence();   // acquire: invalidate stale L1/L2 lines before reads
    }
    __syncthreads();
}

// ---------------------------------------------------------------------------
// Fused recurrence: ONE cooperative launch for all 64 steps.
// Grid 192 = 8 groups x 24 blocks. Group g owns chains [16g, 16g+16):
//   gates phase: blocks l<16 compute chain g*16+l (256 thr x 2 h)
//   proj phase : all 24 blocks, 16M x 64N tile of [16x512]@[512x1536],
//                W fragments RESIDENT IN VGPRs for all 63 steps.
// Group index = blockIdx&7 so a group's blocks share an XCD (L2 locality,
// perf-only assumption). All dependencies are group-local -> 2 group
// barriers per step, no grid-wide sync.
// ---------------------------------------------------------------------------
__global__ __launch_bounds__(256, 1) void fused_steps(
    const int* __restrict__ bfs, const unsigned char* __restrict__ clist,
    const int* __restrict__ ccnt,
    const float* __restrict__ XPi, const float* __restrict__ XPf, const float* __restrict__ XPu,
    const unsigned short* __restrict__ Wihh, const unsigned short* __restrict__ Wihl,
    const unsigned short* __restrict__ Wfhh, const unsigned short* __restrict__ Wfhl,
    const unsigned short* __restrict__ Wuhh, const unsigned short* __restrict__ Wuhl,
    float* __restrict__ HWi, float* __restrict__ HWf, float* __restrict__ HWu,
    float* __restrict__ C, float* __restrict__ hf32,
    unsigned short* __restrict__ h_hi, unsigned short* __restrict__ h_lo,
    int* __restrict__ bars)
{
    const int g = blockIdx.x & 7;          // group (XCD-aligned if round-robin)
    const int l = blockIdx.x >> 3;         // 0..23 within group
    const int tid = threadIdx.x;
    const int m0 = g * 16;                 // first chain of this group

    // proj tile: gate = l>>3, n0 = (l&7)*64
    const int gate = l >> 3;
    const int n0 = (l & 7) * 64;
    const unsigned short* __restrict__ Wbh = (gate == 0) ? Wihh : (gate == 1) ? Wfhh : Wuhh;
    const unsigned short* __restrict__ Wbl = (gate == 0) ? Wihl : (gate == 1) ? Wfhl : Wuhl;
    float* __restrict__ OUT = (gate == 0) ? HWi : (gate == 1) ? HWf : HWu;

    const int lane = tid & 63, wave = tid >> 6;
    const int quad = lane >> 4, col = lane & 15;
    const int wn = wave * 16;              // wave's 16-wide N-slice

    __shared__ unsigned short As[2][16 * 520];   // h hi/lo, 16 rows, pad 520
    __shared__ int s_cur_all[16 * 64];           // bfs row per chain (m*64+t)
    __shared__ unsigned char s_clist[SS * SS];   // this chain's child lists (l<16)
    __shared__ int s_ccnt[SS];

    // ---- one-time init ----
    const int bchain = m0 + l;             // valid only for l < 16
    if (l < 16) {
        const u32x4* src = (const u32x4*)(clist + (size_t)bchain * SS * SS);
        u32x4* dst = (u32x4*)s_clist;
        dst[tid] = src[tid];               // 256 x 16B = 4096 B exactly
        if (tid < SS) s_ccnt[tid] = ccnt[bchain * SS + tid];
    }
    for (int i = tid; i < 16 * 64; i += 256)
        s_cur_all[i] = bfs[(m0 + (i >> 6)) * SS + (i & 63)];

    // ---- W fragments resident in VGPRs (32 x bf16x8 = 128 VGPRs) ----
    bf16x8 wh[16], wl[16];
    {
        const size_t wrow = (size_t)(n0 + wn + col) * HH;
        #pragma unroll
        for (int kq = 0; kq < 16; ++kq) {
            wh[kq] = *(const bf16x8*)(Wbh + wrow + kq * 32 + quad * 8);
            wl[kq] = *(const bf16x8*)(Wbl + wrow + kq * 32 + quad * 8);
        }
    }
    __syncthreads();

    int* gbars = bars + g * 256;

    for (int t = 0; t < SS; ++t) {
        // ================= gates phase (blocks l < 16) =================
        if (l < 16) {
            const int cur = s_cur_all[(l << 6) + t];
            const int cnt = s_ccnt[t];
            const int h2 = tid * 2;
            const size_t xb = ((size_t)bchain * SS + cur) * HH + h2;
            const float2 xpi = *(const float2*)(XPi + xb);   // xe@Wix.T + bix + bih
            const float2 xpf = *(const float2*)(XPf + xb);   // xe@Wfx.T + bfx + bfh
            const float2 xpu = *(const float2*)(XPu + xb);   // xe@Wux.T + bux + buh

            float ai0 = 0.f, ai1 = 0.f, af0 = 0.f, af1 = 0.f;
            float au0 = 0.f, au1 = 0.f, fc0 = 0.f, fc1 = 0.f;
            for (int idx = 0; idx < cnt; ++idx) {
                const int s = s_clist[(t << 6) + idx];
                const size_t cb = ((size_t)bchain * SS + s) * HH + h2;
                const float2 pi = *(const float2*)(HWi + cb);
                const float2 pf = *(const float2*)(HWf + cb);
                const float2 pu = *(const float2*)(HWu + cb);
                const float2 cc = *(const float2*)(C + cb);
                ai0 += pi.x; ai1 += pi.y;
                au0 += pu.x; au1 += pu.y;
                af0 += pf.x; af1 += pf.y;
                fc0 += fast_sigmoid(pf.x + xpf.x) * cc.x;   // per-child forget * C
                fc1 += fast_sigmoid(pf.y + xpf.y) * cc.y;
            }

            const float i0 = fast_sigmoid(xpi.x + ai0), i1 = fast_sigmoid(xpi.y + ai1);
            const float o0 = fast_sigmoid(xpf.x + af0), o1 = fast_sigmoid(xpf.y + af1);
            const float u0 = fast_tanh(xpu.x + au0),    u1 = fast_tanh(xpu.y + au1);
            const float c0 = i0 * u0 + fc0, c1 = i1 * u1 + fc1;
            const float h0 = o0 * fast_tanh(c0), h1 = o1 * fast_tanh(c1);

            *(float2*)(C + xb) = make_float2(c0, c1);
            unsigned short h0h, h0l, h1h, h1l;
            split2(h0, h0h, h0l); split2(h1, h1h, h1l);
            *(unsigned int*)(h_hi + (size_t)bchain * HH + h2) = ((unsigned int)h1h << 16) | h0h;
            *(unsigned int*)(h_lo + (size_t)bchain * HH + h2) = ((unsigned int)h1l << 16) | h0l;
            if (t == SS - 1)
                *(float2*)(hf32 + (size_t)bchain * HH + h2) = make_float2(h0, h1);
        }
        if (t == SS - 1) break;
        group_barrier(gbars + t * 2);

        // ================= proj phase (all 24 blocks) =================
        // stage h rows m0..m0+15 (hi/lo) into LDS: 2048 x 16B chunks / 256 thr
        for (int i = tid; i < 2048; i += 256) {
            const int plane = i >> 10, j = i & 1023, r = j >> 6, c = j & 63;
            const unsigned short* src = plane ? h_lo : h_hi;
            *(u32x4*)&As[plane][r * 520 + c * 8] =
                *(const u32x4*)(src + (size_t)(m0 + r) * HH + c * 8);
        }
        __syncthreads();

        f32x4 accA = {0.f, 0.f, 0.f, 0.f}, accB = {0.f, 0.f, 0.f, 0.f};
        #pragma unroll
        for (int kq = 0; kq < 16; ++kq) {          // K = 512 = 16 * 32
            const int ka = kq * 32 + quad * 8;
            bf16x8 ah = *(const bf16x8*)&As[0][col * 520 + ka];
            bf16x8 al = *(const bf16x8*)&As[1][col * 520 + ka];
            accA = __builtin_amdgcn_mfma_f32_16x16x32_bf16(ah, wh[kq], accA, 0, 0, 0);
            accB = __builtin_amdgcn_mfma_f32_16x16x32_bf16(ah, wl[kq], accB, 0, 0, 0);
            accA = __builtin_amdgcn_mfma_f32_16x16x32_bf16(al, wh[kq], accA, 0, 0, 0);
        }
        const f32x4 acc = accA + accB;

        // scatter: C/D layout col=N, quad*4+reg=M
        #pragma unroll
        for (int reg = 0; reg < 4; ++reg) {
            const int m = quad * 4 + reg;
            const int cur = s_cur_all[(m << 6) + t];
            OUT[((size_t)(m0 + m) * SS + cur) * HH + n0 + wn + col] = acc[reg];
        }
        group_barrier(gbars + t * 2 + 1);
    }
}

// ---------------------------------------------------------------------------
// Final projection: out[b,l] = hcur[b,:] . Wout[l,:] + bout[l]  (fp32)
// ---------------------------------------------------------------------------
__global__ __launch_bounds__(64) void out_kernel(
    const float* __restrict__ hcur,
    const float* __restrict__ Wout, const float* __restrict__ bout,
    float* __restrict__ out)
{
    const int b = blockIdx.x;
    const int lane = threadIdx.x;
    float acc[LL];
    #pragma unroll
    for (int l = 0; l < LL; ++l) acc[l] = 0.0f;
    for (int h = lane; h < HH; h += 64) {
        const float hv = hcur[(size_t)b * HH + h];
        #pragma unroll
        for (int l = 0; l < LL; ++l) acc[l] += hv * Wout[l * HH + h];
    }
    #pragma unroll
    for (int off = 32; off > 0; off >>= 1) {
        #pragma unroll
        for (int l = 0; l < LL; ++l) acc[l] += __shfl_down(acc[l], off);
    }
    if (lane == 0) {
        #pragma unroll
        for (int l = 0; l < LL; ++l) out[b * LL + l] = acc[l] + bout[l];
    }
}

extern "C" void kernel_launch(void* const* d_in, const int* in_sizes, int n_in,
                              void* d_out, int out_size, void* d_ws, size_t ws_size,
                              hipStream_t stream)
{
    (void)in_sizes; (void)n_in; (void)out_size; (void)ws_size;
    const int*   x        = (const int*)d_in[0];
    const int*   bfs      = (const int*)d_in[1];
    const int*   children = (const int*)d_in[2];
    const float* embed    = (const float*)d_in[3];
    const float* Wix = (const float*)d_in[4];
    const float* bix = (const float*)d_in[5];
    const float* Wih = (const float*)d_in[6];
    const float* bih = (const float*)d_in[7];
    const float* Wfx = (const float*)d_in[8];
    const float* bfx = (const float*)d_in[9];
    const float* Wfh = (const float*)d_in[10];
    const float* bfh = (const float*)d_in[11];
    const float* Wux = (const float*)d_in[12];
    const float* bux = (const float*)d_in[13];
    const float* Wuh = (const float*)d_in[14];
    const float* buh = (const float*)d_in[15];
    const float* Wout = (const float*)d_in[16];
    const float* bout = (const float*)d_in[17];
    float* out = (float*)d_out;

    // Workspace layout (~124 MB; every chunk size is a multiple of 256 B)
    char* p = (char*)d_ws;
    float* XPi = (float*)p;            p += (size_t)BSH * 4;
    float* XPf = (float*)p;            p += (size_t)BSH * 4;
    float* XPu = (float*)p;            p += (size_t)BSH * 4;
    float* Cst = (float*)p;            p += (size_t)BSH * 4;
    float* HWi = (float*)p;            p += (size_t)BSH * 4;
    float* HWf = (float*)p;            p += (size_t)BSH * 4;
    float* HWu = (float*)p;            p += (size_t)BSH * 4;
    float* hf32 = (float*)p;           p += (size_t)BB * HH * 4;
    unsigned short* h_hi = (unsigned short*)p; p += (size_t)BB * HH * 2;
    unsigned short* h_lo = (unsigned short*)p; p += (size_t)BB * HH * 2;
    unsigned short* Wixh = (unsigned short*)p; p += (size_t)HH * KP * 2;
    unsigned short* Wixl = (unsigned short*)p; p += (size_t)HH * KP * 2;
    unsigned short* Wfxh = (unsigned short*)p; p += (size_t)HH * KP * 2;
    unsigned short* Wfxl = (unsigned short*)p; p += (size_t)HH * KP * 2;
    unsigned short* Wuxh = (unsigned short*)p; p += (size_t)HH * KP * 2;
    unsigned short* Wuxl = (unsigned short*)p; p += (size_t)HH * KP * 2;
    unsigned short* Wihh = (unsigned short*)p; p += (size_t)HH * HH * 2;
    unsigned short* Wihl = (unsigned short*)p; p += (size_t)HH * HH * 2;
    unsigned short* Wfhh = (unsigned short*)p; p += (size_t)HH * HH * 2;
    unsigned short* Wfhl = (unsigned short*)p; p += (size_t)HH * HH * 2;
    unsigned short* Wuhh = (unsigned short*)p; p += (size_t)HH * HH * 2;
    unsigned short* Wuhl = (unsigned short*)p; p += (size_t)HH * HH * 2;
    unsigned char* clist = (unsigned char*)p;  p += (size_t)BB * SS * SS;
    int* ccnt = (int*)p;               p += (size_t)BB * SS * 4;
    int* bars = (int*)p;               p += (size_t)NGRP * 256 * 4;
    // No zero-init of state arrays needed: gather only touches slots written
    // earlier this call. Barrier counters zeroed by prep_kernel each call.

    prep_kernel<<<dim3(256), 256, 0, stream>>>(
        bfs, children, Wix, Wfx, Wux, Wih, Wfh, Wuh,
        Wixh, Wixl, Wfxh, Wfxl, Wuxh, Wuxl,
        Wihh, Wihl, Wfhh, Wfhl, Wuhh, Wuhl, clist, ccnt, bars);

    xp_mfma<<<dim3(256, 3), 256, 0, stream>>>(
        x, embed, Wixh, Wixl, Wfxh, Wfxl, Wuxh, Wuxl,
        bix, bih, bfx, bfh, bux, buh, XPi, XPf, XPu);

    {
        void* args[] = {
            (void*)&bfs, (void*)&clist, (void*)&ccnt,
            (void*)&XPi, (void*)&XPf, (void*)&XPu,
            (void*)&Wihh, (void*)&Wihl, (void*)&Wfhh, (void*)&Wfhl,
            (void*)&Wuhh, (void*)&Wuhl,
            (void*)&HWi, (void*)&HWf, (void*)&HWu,
            (void*)&Cst, (void*)&hf32, (void*)&h_hi, (void*)&h_lo,
            (void*)&bars
        };
        hipLaunchCooperativeKernel((void*)fused_steps, dim3(GRID_FUSED), dim3(256),
                                   args, 0, stream);
    }

    out_kernel<<<dim3(BB), 64, 0, stream>>>(hf32, Wout, bout, out);
}